// Round 3
// baseline (1274.256 us; speedup 1.0000x reference)
//
#include <hip/hip_runtime.h>

// Problem constants
#define CIN   256
#define COUT  384
#define HH    56
#define WW    56
#define HO    54
#define NB    16
#define NPIX  (NB*HO*HO)   // 46656
#define KK    (CIN*9)      // 2304
#define XCH   (HH*WW)      // 3136
#define XIMG  (CIN*HH*WW)  // 802816

// GEMM tiling
#define BM 128
#define BN 128
#define BK 8

// 16B-chunk swizzle within a 512B LDS row: spreads the 16 distinct
// A-fragment read addresses (32B stride) across all 8 bank groups.
#define CH_SWZ(j) ((j) ^ (((j) >> 3) & 1))

// ws layout: Wt[KK][COUT] fp32 at 0 (3,538,944 B); y[COUT][NPIX] fp32 at 4 MiB (71,663,616 B)
#define WS_Y_OFF (4u << 20)

__global__ __launch_bounds__(256) void wtrans(const float* __restrict__ w,
                                              float* __restrict__ wt) {
    int idx = blockIdx.x * 256 + threadIdx.x;   // KK*COUT = 884736 total
    int k = idx / COUT, c = idx - k * COUT;
    wt[idx] = w[c * KK + k];
}

__global__ __launch_bounds__(256) void conv_gemm(const float* __restrict__ x,
                                                 const float* __restrict__ wt,
                                                 float* __restrict__ y) {
    __shared__ float As[2][BK][BM];
    __shared__ float Bs[2][BK][BN];

    const int tid = threadIdx.x;
    const int c0 = blockIdx.y * BM;
    const int p0 = blockIdx.x * BN;

    // staging mapping: 8 k-rows x 32 chunks of 4 floats
    const int ldk = tid >> 5;            // 0..7
    const int jch = tid & 31;            // logical chunk 0..31
    const int ldc = jch << 2;            // logical column
    const int pst = CH_SWZ(jch) << 2;    // swizzled float offset for staging write

    // pixel base offsets for B staging (clamped if OOB)
    int pb[4];
#pragma unroll
    for (int j = 0; j < 4; ++j) {
        int p = p0 + ldc + j;
        if (p >= NPIX) p = NPIX - 1;
        int b   = p / 2916;
        int rem = p - b * 2916;
        int oy  = rem / 54;
        int ox  = rem - oy * 54;
        pb[j] = b * XIMG + oy * WW + ox;
    }

    // fragment read offsets (swizzled positions; content = logical cols)
    const int i16 = tid & 15;
    const int u   = tid >> 4;
    const int pa0 = CH_SWZ(2 * i16)     << 2;
    const int pa1 = CH_SWZ(2 * i16 + 1) << 2;
    const int pb0 = CH_SWZ(2 * u)       << 2;
    const int pb1 = CH_SWZ(2 * u + 1)   << 2;

    float acc[8][8];
#pragma unroll
    for (int i = 0; i < 8; ++i)
#pragma unroll
        for (int j = 0; j < 8; ++j) acc[i][j] = 0.f;

    float4 aReg;
    float  bReg0, bReg1, bReg2, bReg3;

    // prefetch it=0
    {
        int k = ldk;
        aReg = *(const float4*)(wt + k * COUT + c0 + ldc);
        int cin = k / 9, r = k - cin * 9;
        int dy = r / 3, dx = r - dy * 3;
        int off = cin * XCH + dy * WW + dx;
        bReg0 = x[pb[0] + off];
        bReg1 = x[pb[1] + off];
        bReg2 = x[pb[2] + off];
        bReg3 = x[pb[3] + off];
    }
    // stage buffer 0
    *(float4*)&As[0][ldk][pst] = aReg;
    *(float4*)&Bs[0][ldk][pst] = make_float4(bReg0, bReg1, bReg2, bReg3);
    __syncthreads();

    const int NIT = KK / BK;          // 288
    for (int it = 0; ; ++it) {
        const int cur = it & 1;
        const bool more = (it + 1 < NIT);

        if (more) {                   // issue next-chunk loads; overlap with FMA below
            int k = (it + 1) * BK + ldk;
            aReg = *(const float4*)(wt + k * COUT + c0 + ldc);
            int cin = k / 9, r = k - cin * 9;
            int dy = r / 3, dx = r - dy * 3;
            int off = cin * XCH + dy * WW + dx;
            bReg0 = x[pb[0] + off];
            bReg1 = x[pb[1] + off];
            bReg2 = x[pb[2] + off];
            bReg3 = x[pb[3] + off];
        }

#pragma unroll
        for (int k = 0; k < BK; ++k) {
            float a[8], b[8];
            *(float4*)&a[0] = *(const float4*)&As[cur][k][pa0];
            *(float4*)&a[4] = *(const float4*)&As[cur][k][pa1];
            *(float4*)&b[0] = *(const float4*)&Bs[cur][k][pb0];
            *(float4*)&b[4] = *(const float4*)&Bs[cur][k][pb1];
#pragma unroll
            for (int i = 0; i < 8; ++i)
#pragma unroll
                for (int j = 0; j < 8; ++j)
                    acc[i][j] += a[i] * b[j];
        }

        if (!more) break;
        *(float4*)&As[cur ^ 1][ldk][pst] = aReg;
        *(float4*)&Bs[cur ^ 1][ldk][pst] = make_float4(bReg0, bReg1, bReg2, bReg3);
        __syncthreads();
    }

    // epilogue: y[cout][pixel]
    const int tc = i16 << 3;
    const int tp = u << 3;
    if (p0 + tp < NPIX) {
#pragma unroll
        for (int i = 0; i < 8; ++i) {
            float* dst = y + (c0 + tc + i) * NPIX + p0 + tp;
            *(float4*)dst       = make_float4(acc[i][0], acc[i][1], acc[i][2], acc[i][3]);
            *(float4*)(dst + 4) = make_float4(acc[i][4], acc[i][5], acc[i][6], acc[i][7]);
        }
    }
}

__global__ __launch_bounds__(256) void gate(const float* __restrict__ y,
                                            float* __restrict__ out) {
    __shared__ float ys[COUT][33];    // padded pitch: conflict-free column access
    __shared__ float gtab[COUT];
    __shared__ float pmax[8][32];
    __shared__ float mx[32];
    __shared__ int   wcnt[32];
    __shared__ int   wlist[32][4];

    const int tid = threadIdx.x;
    const int tx = tid & 31, ty = tid >> 5;   // ty 0..7
    const int p0 = blockIdx.x * 32;

    // Gaussian kernel table: kern[k] = exp(-(k-191)^2 / (2*191^2))
    for (int k = tid; k < COUT; k += 256) {
        float d = (float)(k - 191);
        gtab[k] = expf(-d * d * (1.0f / (2.0f * 191.0f * 191.0f)));
    }
    if (ty == 0) wcnt[tx] = 0;

    // stage y tile: 384 channels x 32 pixels (coalesced 128B rows)
    for (int c = ty; c < COUT; c += 8)
        ys[c][tx] = y[c * NPIX + p0 + tx];
    __syncthreads();

    // per-pixel max: 8-way partial then combine
    float m = -3.402823466e+38f;
    for (int c = ty; c < COUT; c += 8) m = fmaxf(m, ys[c][tx]);
    pmax[ty][tx] = m;
    __syncthreads();
    if (ty == 0) {
        float mm = pmax[0][tx];
#pragma unroll
        for (int r = 1; r < 8; ++r) mm = fmaxf(mm, pmax[r][tx]);
        mx[tx] = mm;
    }
    __syncthreads();

    // winner list (ties included)
    const float mm = mx[tx];
    for (int c = ty; c < COUT; c += 8) {
        if (ys[c][tx] >= mm) {
            int pos = atomicAdd(&wcnt[tx], 1);
            if (pos < 4) wlist[tx][pos] = c;
        }
    }
    __syncthreads();

    // gated output, NCHW
    const int p   = p0 + tx;
    const int b   = p / 2916;
    const int rem = p - b * 2916;
    const int obase = b * (COUT * 2916) + rem;
    const int L = min(wcnt[tx], 4);
    for (int c = ty; c < COUT; c += 8) {
        float lfb = 0.f;
        for (int i = 0; i < L; ++i) {
            int d = wlist[tx][i] - c + 191;
            if (d >= 0 && d < COUT) lfb += gtab[d];
        }
        lfb = fminf(lfb, 1.0f);
        out[obase + c * 2916] = lfb * ys[c][tx];
    }
}

extern "C" void kernel_launch(void* const* d_in, const int* in_sizes, int n_in,
                              void* d_out, int out_size, void* d_ws, size_t ws_size,
                              hipStream_t stream) {
    const float* x = (const float*)d_in[0];
    const float* w = (const float*)d_in[1];
    float* outp = (float*)d_out;

    float* wt = (float*)d_ws;                              // 3.46 MB
    float* y  = (float*)((char*)d_ws + WS_Y_OFF);          // 71.7 MB

    wtrans<<<(KK * COUT) / 256, 256, 0, stream>>>(w, wt);

    dim3 grid((NPIX + BN - 1) / BN, COUT / BM);            // (365, 3)
    conv_gemm<<<grid, 256, 0, stream>>>(x, wt, y);

    gate<<<NPIX / 32, 256, 0, stream>>>(y, outp);
}

// Round 4
// 939.103 us; speedup vs baseline: 1.3569x; 1.3569x over previous
//
#include <hip/hip_runtime.h>

// Problem constants
#define CIN   256
#define COUT  384
#define HH    56
#define WW    56
#define HO    54
#define NB    16
#define NPIX  (NB*HO*HO)   // 46656
#define KK    (CIN*9)      // 2304
#define XCH   (HH*WW)      // 3136
#define XIMG  (CIN*HH*WW)  // 802816

#define BM 128
#define BN 128
#define NCHUNK (KK/32)     // 72 chunks of K=32
#define KGRP   (KK/8)      // 288 k-groups of 8
#define WPLANE (KGRP*COUT*8)   // 884736 ushorts per split plane

// ws layout: Wg bf16 splits at 0 (3 planes x 1.77MB = 5.31MB); y[COUT][NPIX] fp32 at 8MiB (71.7MB)
#define WS_Y_OFF (8u << 20)

typedef __bf16  bf16x8 __attribute__((ext_vector_type(8)));
typedef float   f32x4  __attribute__((ext_vector_type(4)));
typedef ushort  us8    __attribute__((ext_vector_type(8)));

__device__ __forceinline__ ushort rne_bf16(float f) {
    unsigned u = __float_as_uint(f);
    return (ushort)((u + 0x7FFFu + ((u >> 16) & 1u)) >> 16);
}
__device__ __forceinline__ void split3(float v, ushort& h1, ushort& h2, ushort& h3) {
    h1 = rne_bf16(v);
    float r1 = v - __uint_as_float((unsigned)h1 << 16);   // exact
    h2 = rne_bf16(r1);
    float r2 = r1 - __uint_as_float((unsigned)h2 << 16);  // exact
    h3 = rne_bf16(r2);
}

// W split + retile: Wg[s][kgrp][cout][kk] bf16, so a 16B chunk is one (kgrp,cout) run
__global__ __launch_bounds__(256) void wsplit(const float* __restrict__ w,
                                              ushort* __restrict__ wg) {
    int idx = blockIdx.x * 256 + threadIdx.x;     // KK*COUT, k fastest -> coalesced read
    int cout = idx / KK, k = idx - cout * KK;
    ushort h1, h2, h3;
    split3(w[idx], h1, h2, h3);
    int base = ((k >> 3) * COUT + cout) * 8 + (k & 7);
    wg[base]              = h1;
    wg[WPLANE + base]     = h2;
    wg[2 * WPLANE + base] = h3;
}

__global__ __launch_bounds__(256, 2) void conv_mfma(const float* __restrict__ x,
                                                    const ushort* __restrict__ wg,
                                                    float* __restrict__ y) {
    // LDS: A/B fragment-native layout [split][kgroup][row][kk8]
    __shared__ __align__(16) ushort As[3][4][128][8];   // 24 KB
    __shared__ __align__(16) ushort Bs[3][4][128][8];   // 24 KB
    __shared__ int offk[KK];                            // 9 KB

    const int tid = threadIdx.x;
    const int c0 = blockIdx.y * BM;   // cout tile base
    const int p0 = blockIdx.x * BN;   // pixel tile base

    // k -> x offset table (computed once)
    for (int k = tid; k < KK; k += 256) {
        int cin = k / 9, r = k - cin * 9;
        int dy = r / 3, dx = r - dy * 3;
        offk[k] = cin * XCH + dy * WW + dx;
    }

    // B staging: thread owns pixel nb, k-groups gb0 and gb0+2
    const int nb  = tid & 127;
    const int gb0 = tid >> 7;          // 0/1
    int pbase;
    {
        int p = p0 + nb; if (p >= NPIX) p = NPIX - 1;
        int b = p / 2916, rem = p - b * 2916;
        int oy = rem / 54, ox = rem - oy * 54;
        pbase = b * XIMG + oy * WW + ox;
    }
    __syncthreads();   // offk ready

    // wave geometry: 4 waves -> 2x2 grid of 64x64 tiles
    const int lane = tid & 63;
    const int wv = tid >> 6;
    const int wr = wv >> 1, wc = wv & 1;
    const int l15 = lane & 15, lg = lane >> 4;
    const int mrow = wr * 64 + l15;
    const int ncol = wc * 64 + l15;

    f32x4 acc[4][4];
#pragma unroll
    for (int i = 0; i < 4; ++i)
#pragma unroll
        for (int j = 0; j < 4; ++j) acc[i][j] = (f32x4)0.f;

    float4 aPre[6];
    float  bPre[2][8];
    us8    bSpl[2][3];

    auto PREFETCH = [&](int c) {
        // A: 6 x 16B chunks per thread (flat = s*512 + g*128 + m)
#pragma unroll
        for (int r = 0; r < 6; ++r) {
            int flat = r * 256 + tid;
            int s = flat >> 9, rem = flat & 511;
            int g = rem >> 7, m = rem & 127;
            aPre[r] = *(const float4*)(wg + ((s * KGRP + (c * 4 + g)) * COUT + (c0 + m)) * 8);
        }
        // B: 2 tasks x 8 scattered (n-coalesced) fp32 loads
#pragma unroll
        for (int t = 0; t < 2; ++t) {
            int kb = c * 32 + (gb0 + 2 * t) * 8;
#pragma unroll
            for (int kk = 0; kk < 8; ++kk)
                bPre[t][kk] = x[pbase + offk[kb + kk]];
        }
    };

    auto SPLITB = [&]() {
#pragma unroll
        for (int t = 0; t < 2; ++t) {
            us8 h1v, h2v, h3v;
#pragma unroll
            for (int kk = 0; kk < 8; ++kk) {
                ushort a, b, c2;
                split3(bPre[t][kk], a, b, c2);
                h1v[kk] = a; h2v[kk] = b; h3v[kk] = c2;
            }
            bSpl[t][0] = h1v; bSpl[t][1] = h2v; bSpl[t][2] = h3v;
        }
    };

    auto WRITE = [&]() {
#pragma unroll
        for (int r = 0; r < 6; ++r) {
            int flat = r * 256 + tid;
            *(float4*)((ushort*)As + flat * 8) = aPre[r];
        }
#pragma unroll
        for (int t = 0; t < 2; ++t) {
            int g = gb0 + 2 * t;
#pragma unroll
            for (int s = 0; s < 3; ++s)
                *(us8*)&Bs[s][g][nb][0] = bSpl[t][s];
        }
    };

    auto COMPUTE = [&]() {
        bf16x8 af[3][4];
#pragma unroll
        for (int s = 0; s < 3; ++s)
#pragma unroll
            for (int mi = 0; mi < 4; ++mi)
                af[s][mi] = *(const bf16x8*)&As[s][lg][mrow + mi * 16][0];
#pragma unroll
        for (int sb = 0; sb < 3; ++sb) {
            bf16x8 bf[4];
#pragma unroll
            for (int ni = 0; ni < 4; ++ni)
                bf[ni] = *(const bf16x8*)&Bs[sb][lg][ncol + ni * 16][0];
#pragma unroll
            for (int sa = 0; sa + sb < 3; ++sa)
#pragma unroll
                for (int mi = 0; mi < 4; ++mi)
#pragma unroll
                    for (int ni = 0; ni < 4; ++ni)
                        acc[mi][ni] = __builtin_amdgcn_mfma_f32_16x16x32_bf16(
                            af[sa][mi], bf[ni], acc[mi][ni], 0, 0, 0);
        }
    };

    PREFETCH(0);
    SPLITB();
    WRITE();
    __syncthreads();

    for (int c = 0; ; ) {
        if (c + 1 < NCHUNK) { PREFETCH(c + 1); SPLITB(); }
        COMPUTE();
        if (++c == NCHUNK) break;
        __syncthreads();
        WRITE();
        __syncthreads();
    }

    // epilogue: y[cout][pixel]; C/D map: col=lane&15, row=(lane>>4)*4+reg
#pragma unroll
    for (int ni = 0; ni < 4; ++ni) {
        int col = p0 + wc * 64 + ni * 16 + l15;
        if (col < NPIX) {
#pragma unroll
            for (int mi = 0; mi < 4; ++mi) {
                int row0 = c0 + wr * 64 + mi * 16 + lg * 4;
#pragma unroll
                for (int j = 0; j < 4; ++j)
                    y[(row0 + j) * NPIX + col] = acc[mi][ni][j];
            }
        }
    }
}

__global__ __launch_bounds__(256) void gate(const float* __restrict__ y,
                                            float* __restrict__ out) {
    __shared__ float ys[COUT][33];
    __shared__ float gtab[COUT];
    __shared__ float pmax[8][32];
    __shared__ float mx[32];
    __shared__ int   wcnt[32];
    __shared__ int   wlist[32][4];

    const int tid = threadIdx.x;
    const int tx = tid & 31, ty = tid >> 5;
    const int p0 = blockIdx.x * 32;

    for (int k = tid; k < COUT; k += 256) {
        float d = (float)(k - 191);
        gtab[k] = expf(-d * d * (1.0f / (2.0f * 191.0f * 191.0f)));
    }
    if (ty == 0) wcnt[tx] = 0;

    for (int c = ty; c < COUT; c += 8)
        ys[c][tx] = y[c * NPIX + p0 + tx];
    __syncthreads();

    float m = -3.402823466e+38f;
    for (int c = ty; c < COUT; c += 8) m = fmaxf(m, ys[c][tx]);
    pmax[ty][tx] = m;
    __syncthreads();
    if (ty == 0) {
        float mm = pmax[0][tx];
#pragma unroll
        for (int r = 1; r < 8; ++r) mm = fmaxf(mm, pmax[r][tx]);
        mx[tx] = mm;
    }
    __syncthreads();

    const float mm = mx[tx];
    for (int c = ty; c < COUT; c += 8) {
        if (ys[c][tx] >= mm) {
            int pos = atomicAdd(&wcnt[tx], 1);
            if (pos < 4) wlist[tx][pos] = c;
        }
    }
    __syncthreads();

    const int p   = p0 + tx;
    const int b   = p / 2916;
    const int rem = p - b * 2916;
    const int obase = b * (COUT * 2916) + rem;
    const int L = min(wcnt[tx], 4);
    for (int c = ty; c < COUT; c += 8) {
        float lfb = 0.f;
        for (int i = 0; i < L; ++i) {
            int d = wlist[tx][i] - c + 191;
            if (d >= 0 && d < COUT) lfb += gtab[d];
        }
        lfb = fminf(lfb, 1.0f);
        out[obase + c * 2916] = lfb * ys[c][tx];
    }
}

extern "C" void kernel_launch(void* const* d_in, const int* in_sizes, int n_in,
                              void* d_out, int out_size, void* d_ws, size_t ws_size,
                              hipStream_t stream) {
    const float* x = (const float*)d_in[0];
    const float* w = (const float*)d_in[1];
    float* outp = (float*)d_out;

    ushort* wg = (ushort*)d_ws;                            // 5.31 MB (3 bf16 planes)
    float*  y  = (float*)((char*)d_ws + WS_Y_OFF);         // 71.7 MB

    wsplit<<<(KK * COUT) / 256, 256, 0, stream>>>(w, wg);

    dim3 grid((NPIX + BN - 1) / BN, COUT / BM);            // (365, 3)
    conv_mfma<<<grid, 256, 0, stream>>>(x, wg, y);

    gate<<<NPIX / 32, 256, 0, stream>>>(y, outp);
}